// Round 2
// baseline (849.990 us; speedup 1.0000x reference)
//
#include <hip/hip_runtime.h>
#include <hip/hip_bf16.h>
#include <stdint.h>

// ---- problem constants ----
#define SEQ    98          // window tokens
#define DIMC   192
#define NHEADS 6
#define HDIM   32
#define NBATCH 2048
#define NWIN   512
#define SCALE  0.17677669529663687f   // 1/sqrt(32)

// ---- ws layout (bytes) ----
#define OFF_QKVW  0u                       // bf16 [576][192]
#define OFF_PROJW 221184u                  // bf16 [192][192]
#define OFF_BIAS  294912u                  // bf16 [6][112][112] (-1e30 for i>=98||j>=98)
#define OFF_FLAGS 445440u                  // int [512]
#define OFF_Q     447488u                  // bf16 [chunk][6][98][32] (x3: q,k,v)
#define PERWIN_E  (NHEADS * SEQ * HDIM)    // 18816 bf16 elems per window per tensor
#define PERWIN_B  ((size_t)PERWIN_E * 2 * 3) // 112896 bytes per window (q+k+v)

typedef __attribute__((ext_vector_type(4)))  float f32x4;
typedef __attribute__((ext_vector_type(16))) float f32x16;
typedef __attribute__((ext_vector_type(8)))  short bf16x8;   // 8 bf16 in 4 VGPRs

static __device__ __forceinline__ uint16_t f2bf(float f) {
    uint32_t u = __builtin_bit_cast(uint32_t, f);
    u += 0x7fffu + ((u >> 16) & 1u);            // RNE (inputs finite)
    return (uint16_t)(u >> 16);
}
static __device__ __forceinline__ float bf2f(uint16_t h) {
    uint32_t u = ((uint32_t)h) << 16;
    return __builtin_bit_cast(float, u);
}

// ---------------- K0: weight conversion + bias gather ----------------
__global__ void __launch_bounds__(256) k_prep(
    const float* __restrict__ qkv_w, const float* __restrict__ proj_w,
    const float* __restrict__ bias_table, const int* __restrict__ rel_idx,
    uint16_t* __restrict__ qkv_wb, uint16_t* __restrict__ proj_wb,
    uint16_t* __restrict__ bias6b)
{
    int idx = blockIdx.x * 256 + threadIdx.x;   // grid covers exactly 222720
    if (idx < 110592) {
        qkv_wb[idx] = f2bf(qkv_w[idx]);
    } else if (idx < 147456) {
        int t = idx - 110592;
        proj_wb[t] = f2bf(proj_w[t]);
    } else {
        int t = idx - 147456;                   // [6][112][112]
        int h = t / (112 * 112);
        int rr = t % (112 * 112);
        int i = rr / 112, j = rr % 112;
        float v = -1e30f;
        if (i < SEQ && j < SEQ) v = bias_table[rel_idx[i * SEQ + j] * NHEADS + h];
        bias6b[t] = f2bf(v);
    }
}

// ---------------- K0a: per-window mask-nonzero flags ----------------
__global__ void __launch_bounds__(256) k_flags(const float* __restrict__ mask,
                                               int* __restrict__ flags)
{
    int w = blockIdx.x;
    __shared__ int sf;
    if (threadIdx.x == 0) sf = 0;
    __syncthreads();
    const float* m = mask + (size_t)w * (SEQ * SEQ);
    int local = 0;
    for (int i = threadIdx.x; i < SEQ * SEQ; i += 256) local |= (m[i] != 0.0f);
    if (local) atomicOr(&sf, 1);
    __syncthreads();
    if (threadIdx.x == 0) flags[w] = sf;
}

// ---------------- K1: QKV GEMM (bf16 MFMA 32x32x16) ----------------
// per block: one window b.  M=128 (rows 98..127 zero), N=576 (18 o-tiles of 32
// == exactly (q|k|v, head)), K=192 (12 k-steps of 16).
__global__ void __launch_bounds__(256) k_qkv(
    const float* __restrict__ x, const float* __restrict__ qkv_b,
    const uint16_t* __restrict__ qkv_wb,
    uint16_t* __restrict__ q_ws, uint16_t* __restrict__ k_ws,
    uint16_t* __restrict__ v_ws, int b0)
{
    __shared__ uint16_t xs[128][200];   // stride 400B: 16B-aligned rows
    const int lb = blockIdx.x, b = b0 + lb, tid = threadIdx.x;
    const int lane = tid & 63, wave = tid >> 6;
    const int l31 = lane & 31, lh = lane >> 5;

    // stage x[b] fp32 -> bf16 LDS
    const float4* x4 = (const float4*)(x + (size_t)b * SEQ * DIMC);
    for (int i = tid; i < SEQ * DIMC / 4; i += 256) {   // 4704
        float4 v = x4[i];
        int row = i / 48, col = (i % 48) * 4;
        union { uint16_t s[4]; uint2 u; } pk;
        pk.s[0] = f2bf(v.x); pk.s[1] = f2bf(v.y);
        pk.s[2] = f2bf(v.z); pk.s[3] = f2bf(v.w);
        *(uint2*)&xs[row][col] = pk.u;
    }
    // zero pad rows 98..127 (cols 0..199)
    for (int i = tid; i < 30 * 100; i += 256) {
        int row = 98 + i / 100, c2 = (i % 100) * 2;
        *(uint32_t*)&xs[row][c2] = 0;
    }
    __syncthreads();

    // mt-outer (A-frags register-resident), o-tiles per wave, B-frags from L2
    for (int mt = 0; mt < 4; mt++) {
        bf16x8 afr[12];
        #pragma unroll
        for (int kk = 0; kk < 12; kk++)
            afr[kk] = *(const bf16x8*)&xs[mt * 32 + l31][kk * 16 + lh * 8];

        for (int ot = wave; ot < 18; ot += 4) {
            const uint16_t* wp = qkv_wb + (size_t)(ot * 32 + l31) * DIMC + lh * 8;
            bf16x8 bfr[12];
            #pragma unroll
            for (int kk = 0; kk < 12; kk++)
                bfr[kk] = *(const bf16x8*)(wp + kk * 16);
            float qb = qkv_b[ot * 32 + l31];

            f32x16 acc;
            #pragma unroll
            for (int i = 0; i < 16; i++) acc[i] = 0.0f;
            #pragma unroll
            for (int kk = 0; kk < 12; kk++)
                acc = __builtin_amdgcn_mfma_f32_32x32x16_bf16(afr[kk], bfr[kk], acc, 0, 0, 0);

            const int sec = ot / 6, head = ot % 6;
            uint16_t* outp = (sec == 0 ? q_ws : sec == 1 ? k_ws : v_ws)
                           + (size_t)(lb * NHEADS + head) * SEQ * HDIM + l31;
            #pragma unroll
            for (int r = 0; r < 16; r++) {
                int row = mt * 32 + 4 * lh + (r & 3) + 8 * (r >> 2);
                if (row < SEQ) outp[row * HDIM] = f2bf(acc[r] + qb);
            }
        }
    }
}

// ---------------- K2: fused attention (6 heads) + proj ----------------
__global__ void __launch_bounds__(256) k_attn(
    const uint16_t* __restrict__ q_ws, const uint16_t* __restrict__ k_ws,
    const uint16_t* __restrict__ v_ws, const uint16_t* __restrict__ bias6b,
    const float* __restrict__ mask, const int* __restrict__ flags,
    const uint16_t* __restrict__ proj_wb, const float* __restrict__ proj_b,
    float* __restrict__ out, int b0)
{
    __shared__ uint16_t att_s[98][200];    // bf16 att output, all heads
    __shared__ uint16_t k_s[98][40];       // [j][d], stride 80B (16B-aligned)
    __shared__ uint16_t vT_s[32][136];     // [d][j], stride 272B, cols 98..135 zero
    __shared__ uint16_t p_s[4][16][40];    // per-wave P slice [row][32 cols]

    const int lb = blockIdx.x, b = b0 + lb, tid = threadIdx.x;
    const int lane = tid & 63, wave = tid >> 6;
    const int l15 = lane & 15, lq = lane >> 4;
    const int useMask = flags[b & (NWIN - 1)];
    const float* maskp = mask + (size_t)(b & (NWIN - 1)) * (SEQ * SEQ);

    // zero vT_s cols 96..135 once (staging rewrites cols<98 each head)
    for (int i = tid; i < 32 * 20; i += 256) {
        int row = i / 20, c = 96 + (i % 20) * 2;
        *(uint32_t*)&vT_s[row][c] = 0;
    }

    for (int h = 0; h < NHEADS; h++) {
        if (h) __syncthreads();
        // stage k and v^T for this head
        const uint32_t* kp = (const uint32_t*)(k_ws + (size_t)(lb * NHEADS + h) * SEQ * HDIM);
        const uint32_t* vp = (const uint32_t*)(v_ws + (size_t)(lb * NHEADS + h) * SEQ * HDIM);
        for (int i = tid; i < SEQ * 16; i += 256) {
            int row = i >> 4, cp = i & 15;
            uint32_t kv = kp[i];
            *(uint32_t*)&k_s[row][cp * 2] = kv;
            uint32_t vv = vp[i];
            vT_s[cp * 2][row]     = (uint16_t)(vv & 0xffff);
            vT_s[cp * 2 + 1][row] = (uint16_t)(vv >> 16);
        }
        __syncthreads();

        for (int mt = wave; mt < 7; mt += 4) {
            int qrow = mt * 16 + l15; qrow = qrow < SEQ ? qrow : SEQ - 1;
            bf16x8 aq = *(const bf16x8*)(q_ws +
                ((size_t)(lb * NHEADS + h) * SEQ + qrow) * HDIM + lq * 8);

            f32x4 sacc[7];
            #pragma unroll
            for (int jt = 0; jt < 7; jt++) {
                int krow = jt * 16 + l15; krow = krow < SEQ ? krow : SEQ - 1;
                bf16x8 bk = *(const bf16x8*)&k_s[krow][lq * 8];
                f32x4 z = {0.f, 0.f, 0.f, 0.f};
                sacc[jt] = __builtin_amdgcn_mfma_f32_16x16x32_bf16(aq, bk, z, 0, 0, 0);
            }

            // epilogue: scale + bias(+mask), then wave-parallel softmax
            float p[7][4], rowmax[4], rowsum[4];
            #pragma unroll
            for (int r = 0; r < 4; r++) rowmax[r] = -3e38f;
            #pragma unroll
            for (int jt = 0; jt < 7; jt++) {
                int j = jt * 16 + l15;
                #pragma unroll
                for (int r = 0; r < 4; r++) {
                    int i_ = mt * 16 + lq * 4 + r;
                    float s = sacc[jt][r] * SCALE +
                              bf2f(bias6b[(h * 112 + i_) * 112 + j]);
                    if (useMask && i_ < SEQ && j < SEQ) s += maskp[i_ * SEQ + j];
                    p[jt][r] = s;
                    rowmax[r] = fmaxf(rowmax[r], s);
                }
            }
            #pragma unroll
            for (int r = 0; r < 4; r++) {
                float m = rowmax[r];
                m = fmaxf(m, __shfl_xor(m, 1));
                m = fmaxf(m, __shfl_xor(m, 2));
                m = fmaxf(m, __shfl_xor(m, 4));
                m = fmaxf(m, __shfl_xor(m, 8));
                rowmax[r] = m; rowsum[r] = 0.f;
            }
            #pragma unroll
            for (int jt = 0; jt < 7; jt++)
                #pragma unroll
                for (int r = 0; r < 4; r++) {
                    float e = __expf(p[jt][r] - rowmax[r]);
                    p[jt][r] = e; rowsum[r] += e;
                }
            #pragma unroll
            for (int r = 0; r < 4; r++) {
                float s2 = rowsum[r];
                s2 += __shfl_xor(s2, 1);
                s2 += __shfl_xor(s2, 2);
                s2 += __shfl_xor(s2, 4);
                s2 += __shfl_xor(s2, 8);
                rowsum[r] = 1.0f / s2;
            }

            // PV: K=112 as 4 slices of 32 (slice 3 zero-padded to 128)
            f32x4 oacc[2];
            oacc[0] = (f32x4){0.f,0.f,0.f,0.f};
            oacc[1] = (f32x4){0.f,0.f,0.f,0.f};
            #pragma unroll
            for (int kk = 0; kk < 4; kk++) {
                int t1 = kk * 2 + 1;
                #pragma unroll
                for (int r = 0; r < 4; r++) {
                    p_s[wave][lq * 4 + r][l15]      = f2bf(p[kk * 2][r]);
                    p_s[wave][lq * 4 + r][16 + l15] = f2bf(t1 < 7 ? p[t1][r] : 0.f);
                }
                bf16x8 ap = *(const bf16x8*)&p_s[wave][l15][lq * 8];
                #pragma unroll
                for (int o = 0; o < 2; o++) {
                    bf16x8 bv = *(const bf16x8*)&vT_s[o * 16 + l15][kk * 32 + lq * 8];
                    oacc[o] = __builtin_amdgcn_mfma_f32_16x16x32_bf16(ap, bv, oacc[o], 0, 0, 0);
                }
            }
            #pragma unroll
            for (int o = 0; o < 2; o++)
                #pragma unroll
                for (int r = 0; r < 4; r++) {
                    int row = mt * 16 + lq * 4 + r;
                    if (row < SEQ)
                        att_s[row][h * HDIM + o * 16 + l15] =
                            f2bf(oacc[o][r] * rowsum[r]);
                }
        }
    }
    __syncthreads();

    // proj: out[b] = att @ proj_w^T + proj_b
    for (int ot = wave; ot < 12; ot += 4) {
        const uint16_t* wp = proj_wb + (size_t)(ot * 16 + l15) * DIMC + lq * 8;
        bf16x8 bw[6];
        #pragma unroll
        for (int kk = 0; kk < 6; kk++) bw[kk] = *(const bf16x8*)(wp + kk * 32);
        float pb = proj_b[ot * 16 + l15];
        for (int mt = 0; mt < 7; mt++) {
            int arow = mt * 16 + l15; arow = arow < SEQ ? arow : SEQ - 1;
            f32x4 pacc = {0.f, 0.f, 0.f, 0.f};
            #pragma unroll
            for (int kk = 0; kk < 6; kk++) {
                bf16x8 aa = *(const bf16x8*)&att_s[arow][kk * 32 + lq * 8];
                pacc = __builtin_amdgcn_mfma_f32_16x16x32_bf16(aa, bw[kk], pacc, 0, 0, 0);
            }
            #pragma unroll
            for (int r = 0; r < 4; r++) {
                int row = mt * 16 + lq * 4 + r;
                if (row < SEQ)
                    out[((size_t)b * SEQ + row) * DIMC + ot * 16 + l15] = pacc[r] + pb;
            }
        }
    }
}

// ---------------- launch ----------------
extern "C" void kernel_launch(void* const* d_in, const int* in_sizes, int n_in,
                              void* d_out, int out_size, void* d_ws, size_t ws_size,
                              hipStream_t stream) {
    const float* x          = (const float*)d_in[0];
    const float* mask       = (const float*)d_in[1];
    const float* qkv_w      = (const float*)d_in[2];
    const float* qkv_b      = (const float*)d_in[3];
    const float* proj_w     = (const float*)d_in[4];
    const float* proj_b     = (const float*)d_in[5];
    const float* bias_table = (const float*)d_in[6];
    const int*   rel_idx    = (const int*)d_in[7];
    float* out = (float*)d_out;
    char*  ws  = (char*)d_ws;

    uint16_t* qkv_wb  = (uint16_t*)(ws + OFF_QKVW);
    uint16_t* proj_wb = (uint16_t*)(ws + OFF_PROJW);
    uint16_t* bias6b  = (uint16_t*)(ws + OFF_BIAS);
    int*      flags   = (int*)(ws + OFF_FLAGS);

    // chunk the batch so q/k/v staging fits in ws_size (single chunk when ample)
    int chunk = NBATCH;
    if (ws_size < (size_t)OFF_Q + (size_t)NBATCH * PERWIN_B) {
        size_t cap = ws_size > OFF_Q ? (ws_size - OFF_Q) / PERWIN_B : 1;
        if (cap < 1) cap = 1;
        if (cap > NBATCH) cap = NBATCH;
        chunk = (int)cap;
    }
    uint16_t* q_ws = (uint16_t*)(ws + OFF_Q);
    uint16_t* k_ws = q_ws + (size_t)chunk * PERWIN_E;
    uint16_t* v_ws = k_ws + (size_t)chunk * PERWIN_E;

    k_prep<<<870, 256, 0, stream>>>(qkv_w, proj_w, bias_table, rel_idx,
                                    qkv_wb, proj_wb, bias6b);
    k_flags<<<NWIN, 256, 0, stream>>>(mask, flags);
    for (int b0 = 0; b0 < NBATCH; b0 += chunk) {
        int nb = chunk < NBATCH - b0 ? chunk : NBATCH - b0;
        k_qkv<<<nb, 256, 0, stream>>>(x, qkv_b, qkv_wb, q_ws, k_ws, v_ws, b0);
        k_attn<<<nb, 256, 0, stream>>>(q_ws, k_ws, v_ws, bias6b, mask, flags,
                                       proj_wb, proj_b, out, b0);
    }
}

// Round 3
// 716.241 us; speedup vs baseline: 1.1867x; 1.1867x over previous
//
#include <hip/hip_runtime.h>
#include <hip/hip_bf16.h>
#include <stdint.h>

// ---- problem constants ----
#define SEQ    98
#define DIMC   192
#define NHEADS 6
#define HDIM   32
#define NBATCH 2048
#define NWIN   512
#define SCALE  0.17677669529663687f   // 1/sqrt(32)

// ---- ws layout (bytes) ----
#define OFF_QKVW  0u                       // bf16 [576][192]
#define OFF_PROJW 221184u                  // bf16 [192][192]
#define OFF_BIAS  294912u                  // bf16 [6][112][112]
#define OFF_FLAGS 445440u                  // int [512]
#define OFF_Q     447488u                  // bf16 [chunk] q,k,v,att
#define PERWIN_E  18816                    // 6*98*32 == 98*192
#define PERWIN_B  ((size_t)PERWIN_E * 2 * 4)  // q+k+v+att bytes per window

typedef __attribute__((ext_vector_type(4)))  float f32x4;
typedef __attribute__((ext_vector_type(8)))  short bf16x8;

static __device__ __forceinline__ uint16_t f2bf(float f) {
    uint32_t u = __builtin_bit_cast(uint32_t, f);
    u += 0x7fffu + ((u >> 16) & 1u);
    return (uint16_t)(u >> 16);
}
static __device__ __forceinline__ float bf2f(uint16_t h) {
    uint32_t u = ((uint32_t)h) << 16;
    return __builtin_bit_cast(float, u);
}
static __device__ __forceinline__ uint32_t cvtpk(float a, float b) {
    uint32_t d;
    asm("v_cvt_pk_bf16_f32 %0, %1, %2" : "=v"(d) : "v"(a), "v"(b));
    return d;   // low half = bf16(a), high = bf16(b)
}

// ---------------- K0: weight conversion + bias gather ----------------
__global__ void __launch_bounds__(256) k_prep(
    const float* __restrict__ qkv_w, const float* __restrict__ proj_w,
    const float* __restrict__ bias_table, const int* __restrict__ rel_idx,
    uint16_t* __restrict__ qkv_wb, uint16_t* __restrict__ proj_wb,
    uint16_t* __restrict__ bias6b)
{
    int idx = blockIdx.x * 256 + threadIdx.x;   // 870*256 = 222720 exactly
    if (idx < 110592) {
        qkv_wb[idx] = f2bf(qkv_w[idx]);
    } else if (idx < 147456) {
        int t = idx - 110592;
        proj_wb[t] = f2bf(proj_w[t]);
    } else {
        int t = idx - 147456;                   // [6][112][112]
        int h = t / (112 * 112);
        int rr = t % (112 * 112);
        int i = rr / 112, j = rr % 112;
        float v = -1e30f;
        if (i < SEQ && j < SEQ) v = bias_table[rel_idx[i * SEQ + j] * NHEADS + h];
        bias6b[t] = f2bf(v);
    }
}

// ---------------- K0a: per-window mask-nonzero flags ----------------
__global__ void __launch_bounds__(256) k_flags(const float* __restrict__ mask,
                                               int* __restrict__ flags)
{
    int w = blockIdx.x;
    __shared__ int sf;
    if (threadIdx.x == 0) sf = 0;
    __syncthreads();
    const float* m = mask + (size_t)w * (SEQ * SEQ);
    int local = 0;
    for (int i = threadIdx.x; i < SEQ * SEQ; i += 256) local |= (m[i] != 0.0f);
    if (local) atomicOr(&sf, 1);
    __syncthreads();
    if (threadIdx.x == 0) flags[w] = sf;
}

// ---------------- K1: QKV GEMM, coalesced writeback ----------------
// block = window. M=112 (7 tiles of 16, tokens>=98 garbage & dropped),
// N=576 as 18 ot of 32 (== (q|k|v, head)), K=192 (6 chunks of 32).
__global__ void __launch_bounds__(256, 4) k_qkv(
    const float* __restrict__ x, const float* __restrict__ qkv_b,
    const uint16_t* __restrict__ qkv_wb,
    uint16_t* __restrict__ q_ws, uint16_t* __restrict__ k_ws,
    uint16_t* __restrict__ v_ws, int b0)
{
    __shared__ uint16_t xs[112][200];       // 44.8KB, rows 16B-aligned
    __shared__ uint16_t obuf[4][16][40];    // per-wave 16x32 bounce, 5.1KB
    const int lb = blockIdx.x, b = b0 + lb, tid = threadIdx.x;
    const int lane = tid & 63, wave = tid >> 6;
    const int l15 = lane & 15, lq = lane >> 4;

    // stage x[b] fp32 -> bf16 LDS (rows 98..111 left uninit: dropped rows)
    const float4* x4 = (const float4*)(x + (size_t)b * SEQ * DIMC);
    for (int i = tid; i < SEQ * DIMC / 4; i += 256) {   // 4704
        float4 v = x4[i];
        int row = i / 48, col = (i % 48) * 4;
        uint2 pk;
        pk.x = cvtpk(v.x, v.y);
        pk.y = cvtpk(v.z, v.w);
        *(uint2*)&xs[row][col] = pk;
    }
    __syncthreads();

    for (int ot = wave; ot < 18; ot += 4) {
        bf16x8 bfr[2][6];
        float qb[2];
        #pragma unroll
        for (int o = 0; o < 2; o++) {
            const uint16_t* wp = qkv_wb + (size_t)(ot * 32 + o * 16 + l15) * DIMC + lq * 8;
            #pragma unroll
            for (int kk = 0; kk < 6; kk++) bfr[o][kk] = *(const bf16x8*)(wp + kk * 32);
            qb[o] = qkv_b[ot * 32 + o * 16 + l15];
        }
        const int sec = ot / 6, head = ot % 6;
        uint16_t* outp = (sec == 0 ? q_ws : sec == 1 ? k_ws : v_ws)
                       + (size_t)(lb * NHEADS + head) * (SEQ * HDIM);
        for (int mt = 0; mt < 7; mt++) {
            bf16x8 afr[6];
            #pragma unroll
            for (int kk = 0; kk < 6; kk++)
                afr[kk] = *(const bf16x8*)&xs[mt * 16 + l15][kk * 32 + lq * 8];
            f32x4 a0 = {0.f,0.f,0.f,0.f}, a1 = {0.f,0.f,0.f,0.f};
            #pragma unroll
            for (int kk = 0; kk < 6; kk++) {
                a0 = __builtin_amdgcn_mfma_f32_16x16x32_bf16(afr[kk], bfr[0][kk], a0, 0, 0, 0);
                a1 = __builtin_amdgcn_mfma_f32_16x16x32_bf16(afr[kk], bfr[1][kk], a1, 0, 0, 0);
            }
            // bounce: D row = lq*4+r, col = o*16+l15 (per-wave, no barrier)
            #pragma unroll
            for (int r = 0; r < 4; r++) {
                obuf[wave][lq * 4 + r][l15]      = f2bf(a0[r] + qb[0]);
                obuf[wave][lq * 4 + r][16 + l15] = f2bf(a1[r] + qb[1]);
            }
            int r16 = lane >> 2, m8 = (lane & 3) * 8;
            int token = mt * 16 + r16;
            bf16x8 ov = *(const bf16x8*)&obuf[wave][r16][m8];
            if (token < SEQ)
                *(bf16x8*)(outp + token * HDIM + m8) = ov;   // 1KB/tile contiguous
        }
    }
}

// ---------------- K2: attention, one block per (window, head) ----------------
__global__ void __launch_bounds__(256, 4) k_attn(
    const uint16_t* __restrict__ q_ws, const uint16_t* __restrict__ k_ws,
    const uint16_t* __restrict__ v_ws, const uint16_t* __restrict__ bias6b,
    const float* __restrict__ mask, const int* __restrict__ flags,
    uint16_t* __restrict__ att, int b0)
{
    __shared__ uint16_t k_s[98][40];       // 7.84KB
    __shared__ uint16_t vT_s[32][136];     // 8.7KB, cols 98..135 zeroed
    __shared__ uint16_t ps[4][16][40];     // per-wave P-frag / out bounce

    const int bid = blockIdx.x;
    const int lb = bid / 6, h = bid % 6;
    const int bg = b0 + lb;
    const int tid = threadIdx.x, lane = tid & 63, wave = tid >> 6;
    const int l15 = lane & 15, lq = lane >> 4;
    const int useMask = flags[bg & (NWIN - 1)];
    const float* maskp = mask + (size_t)(bg & (NWIN - 1)) * (SEQ * SEQ);

    // zero vT pad cols 98..135
    for (int i = tid; i < 32 * 19; i += 256) {
        int d = i / 19, c = 98 + (i % 19) * 2;
        *(uint32_t*)&vT_s[d][c] = 0;
    }
    // stage k row-major, v transposed
    const uint32_t* kp = (const uint32_t*)(k_ws + (size_t)(lb * NHEADS + h) * (SEQ * HDIM));
    const uint32_t* vp = (const uint32_t*)(v_ws + (size_t)(lb * NHEADS + h) * (SEQ * HDIM));
    for (int i = tid; i < SEQ * 16; i += 256) {
        int row = i >> 4, cp = i & 15;
        uint32_t kv = kp[i];
        *(uint32_t*)&k_s[row][cp * 2] = kv;
        uint32_t vv = vp[i];
        vT_s[cp * 2][row]     = (uint16_t)(vv & 0xffff);
        vT_s[cp * 2 + 1][row] = (uint16_t)(vv >> 16);
    }
    __syncthreads();

    const uint16_t* qbase = q_ws + (size_t)(lb * NHEADS + h) * (SEQ * HDIM);
    for (int mt = wave; mt < 7; mt += 4) {
        int qrow = mt * 16 + l15; if (qrow > 97) qrow = 97;
        bf16x8 aq = *(const bf16x8*)(qbase + qrow * HDIM + lq * 8);

        float p[7][4], rowmax[4], rowsum[4];
        #pragma unroll
        for (int r = 0; r < 4; r++) rowmax[r] = -3e38f;
        #pragma unroll
        for (int jt = 0; jt < 7; jt++) {
            int krow = jt * 16 + l15; if (krow > 97) krow = 97;
            bf16x8 bk = *(const bf16x8*)&k_s[krow][lq * 8];
            f32x4 z = {0.f,0.f,0.f,0.f};
            f32x4 s4 = __builtin_amdgcn_mfma_f32_16x16x32_bf16(aq, bk, z, 0, 0, 0);
            int j = jt * 16 + l15;
            #pragma unroll
            for (int r = 0; r < 4; r++) {
                int i_ = mt * 16 + lq * 4 + r;
                float s = s4[r] * SCALE + bf2f(bias6b[(h * 112 + i_) * 112 + j]);
                if (useMask && i_ < SEQ && j < SEQ) s += maskp[i_ * SEQ + j];
                p[jt][r] = s;
                rowmax[r] = fmaxf(rowmax[r], s);
            }
        }
        #pragma unroll
        for (int r = 0; r < 4; r++) {
            float m = rowmax[r];
            m = fmaxf(m, __shfl_xor(m, 1));
            m = fmaxf(m, __shfl_xor(m, 2));
            m = fmaxf(m, __shfl_xor(m, 4));
            m = fmaxf(m, __shfl_xor(m, 8));
            rowmax[r] = m; rowsum[r] = 0.f;
        }
        #pragma unroll
        for (int jt = 0; jt < 7; jt++)
            #pragma unroll
            for (int r = 0; r < 4; r++) {
                float e = __expf(p[jt][r] - rowmax[r]);
                p[jt][r] = e; rowsum[r] += e;
            }
        #pragma unroll
        for (int r = 0; r < 4; r++) {
            float s2 = rowsum[r];
            s2 += __shfl_xor(s2, 1); s2 += __shfl_xor(s2, 2);
            s2 += __shfl_xor(s2, 4); s2 += __shfl_xor(s2, 8);
            rowsum[r] = 1.0f / s2;
        }

        // PV: K=112 padded to 128, 4 chunks of 32
        f32x4 o0 = {0.f,0.f,0.f,0.f}, o1 = {0.f,0.f,0.f,0.f};
        #pragma unroll
        for (int kk = 0; kk < 4; kk++) {
            #pragma unroll
            for (int r = 0; r < 4; r++) {
                ps[wave][lq * 4 + r][l15]      = f2bf(p[2 * kk][r]);
                ps[wave][lq * 4 + r][16 + l15] = f2bf(2 * kk + 1 < 7 ? p[2 * kk + 1][r] : 0.f);
            }
            bf16x8 ap  = *(const bf16x8*)&ps[wave][l15][lq * 8];
            bf16x8 bv0 = *(const bf16x8*)&vT_s[l15][kk * 32 + lq * 8];
            bf16x8 bv1 = *(const bf16x8*)&vT_s[16 + l15][kk * 32 + lq * 8];
            o0 = __builtin_amdgcn_mfma_f32_16x16x32_bf16(ap, bv0, o0, 0, 0, 0);
            o1 = __builtin_amdgcn_mfma_f32_16x16x32_bf16(ap, bv1, o1, 0, 0, 0);
        }
        // bounce to coalesced att store
        #pragma unroll
        for (int r = 0; r < 4; r++) {
            ps[wave][lq * 4 + r][l15]      = f2bf(o0[r] * rowsum[r]);
            ps[wave][lq * 4 + r][16 + l15] = f2bf(o1[r] * rowsum[r]);
        }
        int r16 = lane >> 2, m8 = (lane & 3) * 8;
        int token = mt * 16 + r16;
        bf16x8 ov = *(const bf16x8*)&ps[wave][r16][m8];
        if (token < SEQ)
            *(bf16x8*)(att + ((size_t)lb * SEQ + token) * DIMC + h * HDIM + m8) = ov;
    }
}

// ---------------- K3: output projection GEMM ----------------
// M = nb*98 rows of att [M][192] bf16 -> out [M][192] fp32. 64 rows/block.
__global__ void __launch_bounds__(256, 4) k_proj(
    const uint16_t* __restrict__ att, const uint16_t* __restrict__ proj_wb,
    const float* __restrict__ proj_b, float* __restrict__ out, int M)
{
    __shared__ uint16_t as_[64][200];   // 25.6KB
    const int blk = blockIdx.x, tid = threadIdx.x;
    const int lane = tid & 63, wave = tid >> 6;
    const int l15 = lane & 15, lq = lane >> 4;

    for (int i = tid; i < 64 * DIMC / 8; i += 256) {   // 1536
        int el = i * 8;
        int lr = el / DIMC, c = el % DIMC;
        int gr = blk * 64 + lr; if (gr >= M) gr = M - 1;
        *(bf16x8*)&as_[lr][c] = *(const bf16x8*)(att + (size_t)gr * DIMC + c);
    }
    __syncthreads();

    bf16x8 a[6];
    #pragma unroll
    for (int kk = 0; kk < 6; kk++)
        a[kk] = *(const bf16x8*)&as_[wave * 16 + l15][kk * 32 + lq * 8];

    for (int ot = 0; ot < 12; ot++) {
        const uint16_t* wp = proj_wb + (size_t)(ot * 16 + l15) * DIMC + lq * 8;
        f32x4 acc = {0.f,0.f,0.f,0.f};
        #pragma unroll
        for (int kk = 0; kk < 6; kk++) {
            bf16x8 bw = *(const bf16x8*)(wp + kk * 32);
            acc = __builtin_amdgcn_mfma_f32_16x16x32_bf16(a[kk], bw, acc, 0, 0, 0);
        }
        float pb = proj_b[ot * 16 + l15];
        #pragma unroll
        for (int r = 0; r < 4; r++) {
            int gr = blk * 64 + wave * 16 + lq * 4 + r;
            if (gr < M) out[(size_t)gr * DIMC + ot * 16 + l15] = acc[r] + pb;
        }
    }
}

// ---------------- launch ----------------
extern "C" void kernel_launch(void* const* d_in, const int* in_sizes, int n_in,
                              void* d_out, int out_size, void* d_ws, size_t ws_size,
                              hipStream_t stream) {
    const float* x          = (const float*)d_in[0];
    const float* mask       = (const float*)d_in[1];
    const float* qkv_w      = (const float*)d_in[2];
    const float* qkv_b      = (const float*)d_in[3];
    const float* proj_w     = (const float*)d_in[4];
    const float* proj_b     = (const float*)d_in[5];
    const float* bias_table = (const float*)d_in[6];
    const int*   rel_idx    = (const int*)d_in[7];
    float* out = (float*)d_out;
    char*  ws  = (char*)d_ws;

    uint16_t* qkv_wb  = (uint16_t*)(ws + OFF_QKVW);
    uint16_t* proj_wb = (uint16_t*)(ws + OFF_PROJW);
    uint16_t* bias6b  = (uint16_t*)(ws + OFF_BIAS);
    int*      flags   = (int*)(ws + OFF_FLAGS);

    int chunk = NBATCH;
    if (ws_size < (size_t)OFF_Q + (size_t)NBATCH * PERWIN_B) {
        size_t cap = ws_size > OFF_Q ? (ws_size - OFF_Q) / PERWIN_B : 1;
        if (cap < 1) cap = 1;
        if (cap > NBATCH) cap = NBATCH;
        chunk = (int)cap;
    }
    uint16_t* q_ws   = (uint16_t*)(ws + OFF_Q);
    uint16_t* k_ws   = q_ws + (size_t)chunk * PERWIN_E;
    uint16_t* v_ws   = k_ws + (size_t)chunk * PERWIN_E;
    uint16_t* att_ws = v_ws + (size_t)chunk * PERWIN_E;

    k_prep<<<870, 256, 0, stream>>>(qkv_w, proj_w, bias_table, rel_idx,
                                    qkv_wb, proj_wb, bias6b);
    k_flags<<<NWIN, 256, 0, stream>>>(mask, flags);
    for (int b0 = 0; b0 < NBATCH; b0 += chunk) {
        int nb = chunk < NBATCH - b0 ? chunk : NBATCH - b0;
        k_qkv<<<nb, 256, 0, stream>>>(x, qkv_b, qkv_wb, q_ws, k_ws, v_ws, b0);
        k_attn<<<nb * NHEADS, 256, 0, stream>>>(q_ws, k_ws, v_ws, bias6b, mask,
                                                flags, att_ws, b0);
        int M = nb * SEQ;
        k_proj<<<(M + 63) / 64, 256, 0, stream>>>(att_ws, proj_wb, proj_b,
                                                  out + (size_t)b0 * SEQ * DIMC, M);
    }
}